// Round 2
// baseline (425.284 us; speedup 1.0000x reference)
//
#include <hip/hip_runtime.h>

// R2: two-kernel structure.
//  A (1024 blocks): streams noise (256 MiB, the HBM roofline term) with a
//    barrier-free per-wave i-reduction -> nsum[16384][128] in ws. Blocks
//    0..511 also run the per-row linear transforms (+Ddiv) as a prologue,
//    hidden under the stream.
//  B (512 blocks, one per (b,k)): scores, softmaxes, S/32, wfo, u, then the
//    j-loop: wav from LDS-staged nsum/Ddiv, 64x128 matvec, leaky, dot W2.
//
// Shapes: B=16, N=32, D=128, N_ACT=16, D_OA_IN=144, HID=64.

// workspace layout (float offsets)
#define WS_K    0         // [512][128]
#define WS_Q    65536
#define WS_VA   131072
#define WS_KO   196608
#define WS_QO   262144
#define WS_AVO  327680
#define WS_DDIV 393216    // (Vp-Va)/32  [512][128]
#define WS_NSUM 458752    // sum_i noise [16384][128]
// end: 2555904 floats = 10.2 MB

// ---------------------------------------------------------------------------
// Kernel A
// ---------------------------------------------------------------------------
__global__ __launch_bounds__(256) void kA(
    const float* __restrict__ states, const float* __restrict__ policies,
    const float* __restrict__ actions,
    const float* __restrict__ Wk_oa, const float* __restrict__ Wq_oa,
    const float* __restrict__ Wv_oa, const float* __restrict__ Wk_o,
    const float* __restrict__ Wq_o,  const float* __restrict__ Wv_o,
    const float* __restrict__ noise, float* __restrict__ ws)
{
    const int t   = threadIdx.x;
    const int blk = blockIdx.x;

    __shared__ __align__(16) float xa[160];  // [0:144) obs_actions, [144:160) pol-act

    // ---- prologue: row transforms (blocks 0..511 only) ----
    if (blk < 512) {
        const int row = blk;
        if (t < 128)       xa[t] = states[row * 128 + t];
        else if (t < 144)  xa[t] = actions[row * 16 + (t - 128)];
        else if (t < 160) {
            int c = t - 144;
            xa[t] = policies[row * 16 + c] - actions[row * 16 + c];
        }
        __syncthreads();

        for (int u = t; u < 896; u += 256) {
            const int m = u >> 7, o = u & 127;
            const float* Wrow; int len4; float* dst; const float* xsrc = xa;
            switch (m) {
                case 0: Wrow = Wk_oa + o * 144; len4 = 36; dst = ws + WS_K;  break;
                case 1: Wrow = Wq_oa + o * 144; len4 = 36; dst = ws + WS_Q;  break;
                case 2: Wrow = Wv_oa + o * 144; len4 = 36; dst = ws + WS_VA; break;
                case 3: Wrow = Wk_o  + o * 128; len4 = 32; dst = ws + WS_KO; break;
                case 4: Wrow = Wq_o  + o * 128; len4 = 32; dst = ws + WS_QO; break;
                case 5: Wrow = Wv_o  + o * 128; len4 = 32; dst = ws + WS_AVO;break;
                default:Wrow = Wv_oa + o * 144 + 128; len4 = 4;
                        dst = ws + WS_DDIV; xsrc = xa + 144; break;
            }
            const float4* W4 = (const float4*)Wrow;
            const float4* x4 = (const float4*)xsrc;
            float acc = 0.f;
            for (int c = 0; c < len4; ++c) {
                float4 w = W4[c], x = x4[c];
                acc += w.x * x.x + w.y * x.y + w.z * x.z + w.w * x.w;
            }
            dst[row * 128 + o] = (m == 6) ? acc * (1.f / 32.f) : acc;
        }
    }

    // ---- streaming noise reduction: barrier-free, one wave per 16 KiB slab ----
    const int bk   = blk >> 1;
    const int j0   = (blk & 1) * 16;
    const int w    = t >> 6, lane = t & 63;
    const float4* noise4 = (const float4*)noise;
    float4* nsum4 = (float4*)(ws + WS_NSUM);

    #pragma unroll
    for (int s = 0; s < 4; ++s) {
        const int j = j0 + 4 * s + w;
        const float4* p = noise4 + (size_t)(bk * 32 + j) * 1024 + lane;
        // lane covers d-quad (lane&31), i = (lane>>5) + 2r
        float4 a0 = p[0], a1 = p[64], a2 = p[128], a3 = p[192];
        #pragma unroll
        for (int r = 4; r < 16; r += 4) {
            float4 v0 = p[(r + 0) * 64], v1 = p[(r + 1) * 64];
            float4 v2 = p[(r + 2) * 64], v3 = p[(r + 3) * 64];
            a0.x += v0.x; a0.y += v0.y; a0.z += v0.z; a0.w += v0.w;
            a1.x += v1.x; a1.y += v1.y; a1.z += v1.z; a1.w += v1.w;
            a2.x += v2.x; a2.y += v2.y; a2.z += v2.z; a2.w += v2.w;
            a3.x += v3.x; a3.y += v3.y; a3.z += v3.z; a3.w += v3.w;
        }
        float4 sum;
        sum.x = (a0.x + a1.x) + (a2.x + a3.x);
        sum.y = (a0.y + a1.y) + (a2.y + a3.y);
        sum.z = (a0.z + a1.z) + (a2.z + a3.z);
        sum.w = (a0.w + a1.w) + (a2.w + a3.w);
        sum.x += __shfl_xor(sum.x, 32, 64);
        sum.y += __shfl_xor(sum.y, 32, 64);
        sum.z += __shfl_xor(sum.z, 32, 64);
        sum.w += __shfl_xor(sum.w, 32, 64);
        if (lane < 32) nsum4[(size_t)(bk * 32 + j) * 32 + lane] = sum;
    }
}

// ---------------------------------------------------------------------------
// Kernel B: one block per (b,k)
// ---------------------------------------------------------------------------
__global__ __launch_bounds__(256) void kB(
    const float* __restrict__ W1, const float* __restrict__ W2,
    const float* __restrict__ ws, float* __restrict__ out)
{
    const float* Kk  = ws + WS_K;
    const float* Q   = ws + WS_Q;
    const float* Va  = ws + WS_VA;
    const float* Ko  = ws + WS_KO;
    const float* Qo  = ws + WS_QO;
    const float* AVO = ws + WS_AVO;
    const float* Ddiv= ws + WS_DDIV;
    const float* Nsum= ws + WS_NSUM;

    const int bk = blockIdx.x;
    const int b  = bk >> 5;
    const int t  = threadIdx.x;
    const int h  = t >> 2, q = t & 3;
    const int lane = t & 63, w = t >> 6;

    __shared__ __align__(16) float kr[128], kor[128], wfo[128], sdiv[128];
    __shared__ __align__(16) float dd_s[32 * 128];   // Ddiv rows of batch b
    __shared__ __align__(16) float nw_s[32 * 128];   // nsum -> wav in place
    __shared__ float sA[32], sO[32], woa[32], wo[32], u_s[64], jpart[128];

    // stage Ddiv (batch) + nsum (this bk) into LDS; coalesced float4
    {
        const float4* dsrc = (const float4*)(Ddiv + b * 4096);
        const float4* nsrc = (const float4*)(Nsum + (size_t)bk * 4096);
        float4* ddst = (float4*)dd_s;
        float4* ndst = (float4*)nw_s;
        #pragma unroll
        for (int s = 0; s < 4; ++s) {
            ddst[t + 256 * s] = dsrc[t + 256 * s];
            ndst[t + 256 * s] = nsrc[t + 256 * s];
        }
    }
    if (t < 128) { kr[t] = Kk[bk * 128 + t]; kor[t] = Ko[bk * 128 + t]; }

    // per-thread W1b chunk: rows h, cols 128 + q*32 .. +32
    float w1r[32];
    {
        const float4* p = (const float4*)(W1 + h * 256 + 128 + q * 32);
        #pragma unroll
        for (int c = 0; c < 8; ++c) {
            float4 v = p[c];
            w1r[4*c] = v.x; w1r[4*c+1] = v.y; w1r[4*c+2] = v.z; w1r[4*c+3] = v.w;
        }
    }
    const float w2_h = W2[h];
    __syncthreads();

    // scores: i = t>>3, 8 lanes per dot
    {
        const int i = t >> 3, seg = t & 7;
        const float4* q4  = (const float4*)(Q  + (b * 32 + i) * 128) + seg * 4;
        const float4* qo4 = (const float4*)(Qo + (b * 32 + i) * 128) + seg * 4;
        const float4* k4  = (const float4*)kr  + seg * 4;
        const float4* ko4 = (const float4*)kor + seg * 4;
        float a0 = 0.f, a1 = 0.f;
        #pragma unroll
        for (int c = 0; c < 4; ++c) {
            float4 qv = q4[c], kv = k4[c];
            a0 += qv.x * kv.x + qv.y * kv.y + qv.z * kv.z + qv.w * kv.w;
            float4 pv = qo4[c], mv = ko4[c];
            a1 += pv.x * mv.x + pv.y * mv.y + pv.z * mv.z + pv.w * mv.w;
        }
        #pragma unroll
        for (int off = 1; off < 8; off <<= 1) {
            a0 += __shfl_xor(a0, off, 64);
            a1 += __shfl_xor(a1, off, 64);
        }
        if (seg == 0) {
            const float scale = 0.08838834764831845f;  // 1/sqrt(128)
            sA[i] = a0 * scale;
            sO[i] = a1 * scale;
        }
    }
    __syncthreads();

    // softmaxes in wave 0
    if (t < 64) {
        const int i = t & 31;
        float s = (t < 32) ? sA[i] : sO[i];
        float m = s;
        #pragma unroll
        for (int off = 1; off < 32; off <<= 1) m = fmaxf(m, __shfl_xor(m, off, 64));
        float e = __expf(s - m);
        float sum = e;
        #pragma unroll
        for (int off = 1; off < 32; off <<= 1) sum += __shfl_xor(sum, off, 64);
        float wv = e / sum;
        if (t < 32) { woa[i] = wv; out[16384 + bk * 32 + i] = wv; }
        else        { wo[i]  = wv; out[32768 + bk * 32 + i] = wv; }
    }
    __syncthreads();

    // S/32 (t<128) and wfo (t>=128)
    {
        const int d = t & 127;
        const float* M  = (t < 128) ? Va  : AVO;
        const float* wp = (t < 128) ? woa : wo;
        float acc = 0.f;
        #pragma unroll 8
        for (int i = 0; i < 32; ++i) acc += wp[i] * M[(b * 32 + i) * 128 + d];
        if (t < 128) sdiv[d] = acc * (1.f / 32.f);
        else         wfo[d]  = acc * (1.f / 32.f);
    }
    __syncthreads();

    // u[h] = W1[h,0:128] . wfo
    {
        const float4* w4 = (const float4*)(W1 + h * 256) + q * 8;
        const float4* f4 = (const float4*)wfo + q * 8;
        float acc = 0.f;
        #pragma unroll
        for (int c = 0; c < 8; ++c) {
            float4 wv = w4[c], fv = f4[c];
            acc += wv.x * fv.x + wv.y * fv.y + wv.z * fv.z + wv.w * fv.w;
        }
        acc += __shfl_xor(acc, 1, 64);
        acc += __shfl_xor(acc, 2, 64);
        if (q == 0) u_s[h] = acc;
    }
    // wav in place: nw_s[j][d] = nsum*(0.1/32) + sdiv[d] + dd[j][d]*woa[j] - 0.05
    {
        const int d = t & 127, jb = t >> 7;
        #pragma unroll
        for (int s = 0; s < 16; ++s) {
            const int j = jb + 2 * s;
            nw_s[j * 128 + d] = nw_s[j * 128 + d] * (0.1f / 32.f)
                              + sdiv[d] + dd_s[j * 128 + d] * woa[j] - 0.05f;
        }
    }
    __syncthreads();

    // value loop: no barriers inside
    #pragma unroll 2
    for (int j = 0; j < 32; ++j) {
        const float4* wv4 = (const float4*)(nw_s + j * 128 + q * 32);
        float acc = 0.f;
        #pragma unroll
        for (int c = 0; c < 8; ++c) {
            float4 v = wv4[c];
            acc += w1r[4*c] * v.x + w1r[4*c+1] * v.y
                 + w1r[4*c+2] * v.z + w1r[4*c+3] * v.w;
        }
        acc += __shfl_xor(acc, 1, 64);
        acc += __shfl_xor(acc, 2, 64);
        float hv = u_s[h] + acc;
        hv = (hv > 0.f) ? hv : 0.01f * hv;
        float vp = (q == 0) ? hv * w2_h : 0.f;
        #pragma unroll
        for (int off = 4; off < 64; off <<= 1) vp += __shfl_xor(vp, off, 64);
        if (lane == 0) jpart[j * 4 + w] = vp;
    }
    __syncthreads();
    if (t < 32)
        out[bk * 32 + t] = jpart[t*4] + jpart[t*4+1] + jpart[t*4+2] + jpart[t*4+3];
}

extern "C" void kernel_launch(void* const* d_in, const int* in_sizes, int n_in,
                              void* d_out, int out_size, void* d_ws, size_t ws_size,
                              hipStream_t stream) {
    const float* states   = (const float*)d_in[0];
    const float* policies = (const float*)d_in[1];
    const float* actions  = (const float*)d_in[2];
    const float* noise    = (const float*)d_in[3];
    const float* Wk_oa    = (const float*)d_in[4];
    const float* Wq_oa    = (const float*)d_in[5];
    const float* Wv_oa    = (const float*)d_in[6];
    const float* Wk_o     = (const float*)d_in[7];
    const float* Wq_o     = (const float*)d_in[8];
    const float* Wv_o     = (const float*)d_in[9];
    const float* W1       = (const float*)d_in[10];
    const float* W2       = (const float*)d_in[11];
    float* out = (float*)d_out;
    float* ws  = (float*)d_ws;

    kA<<<1024, 256, 0, stream>>>(states, policies, actions,
                                 Wk_oa, Wq_oa, Wv_oa, Wk_o, Wq_o, Wv_o,
                                 noise, ws);
    kB<<<512, 256, 0, stream>>>(W1, W2, ws, out);
}

// Round 3
// 419.061 us; speedup vs baseline: 1.0149x; 1.0149x over previous
//
#include <hip/hip_runtime.h>

// R3: same two-kernel structure as R2, with:
//  - kA grid 2048 (one wave per 16 KiB j-slab, 2 slabs/wave) for more
//    outstanding HBM loads; transforms prologue still hidden in blocks 0..511.
//  - kB: padded wav LDS layout (rows of 144 floats, q-chunk at q*36) to kill
//    the 4-way ds_read_b128 bank conflict in the j-loop.
//
// Shapes: B=16, N=32, D=128, N_ACT=16, D_OA_IN=144, HID=64.
// noise: [16,32,32,32,128] f32 = 256 MiB -> the controllable HBM floor (~43us).

// workspace layout (float offsets)
#define WS_K    0         // [512][128]
#define WS_Q    65536
#define WS_VA   131072
#define WS_KO   196608
#define WS_QO   262144
#define WS_AVO  327680
#define WS_DDIV 393216    // (Vp-Va)/32  [512][128]
#define WS_NSUM 458752    // sum_i noise [16384][128]

// ---------------------------------------------------------------------------
// Kernel A: transforms prologue (blocks<512) + barrier-free noise reduction.
// grid = 2048; wave gw = blk*4+w handles slabs gw and gw+8192 (slab = (bk,j)).
// ---------------------------------------------------------------------------
__global__ __launch_bounds__(256) void kA(
    const float* __restrict__ states, const float* __restrict__ policies,
    const float* __restrict__ actions,
    const float* __restrict__ Wk_oa, const float* __restrict__ Wq_oa,
    const float* __restrict__ Wv_oa, const float* __restrict__ Wk_o,
    const float* __restrict__ Wq_o,  const float* __restrict__ Wv_o,
    const float* __restrict__ noise, float* __restrict__ ws)
{
    const int t   = threadIdx.x;
    const int blk = blockIdx.x;

    __shared__ __align__(16) float xa[160];  // [0:144) obs_actions, [144:160) pol-act

    if (blk < 512) {
        const int row = blk;
        if (t < 128)       xa[t] = states[row * 128 + t];
        else if (t < 144)  xa[t] = actions[row * 16 + (t - 128)];
        else if (t < 160) {
            int c = t - 144;
            xa[t] = policies[row * 16 + c] - actions[row * 16 + c];
        }
        __syncthreads();

        for (int u = t; u < 896; u += 256) {
            const int m = u >> 7, o = u & 127;
            const float* Wrow; int len4; float* dst; const float* xsrc = xa;
            switch (m) {
                case 0: Wrow = Wk_oa + o * 144; len4 = 36; dst = ws + WS_K;  break;
                case 1: Wrow = Wq_oa + o * 144; len4 = 36; dst = ws + WS_Q;  break;
                case 2: Wrow = Wv_oa + o * 144; len4 = 36; dst = ws + WS_VA; break;
                case 3: Wrow = Wk_o  + o * 128; len4 = 32; dst = ws + WS_KO; break;
                case 4: Wrow = Wq_o  + o * 128; len4 = 32; dst = ws + WS_QO; break;
                case 5: Wrow = Wv_o  + o * 128; len4 = 32; dst = ws + WS_AVO;break;
                default:Wrow = Wv_oa + o * 144 + 128; len4 = 4;
                        dst = ws + WS_DDIV; xsrc = xa + 144; break;
            }
            const float4* W4 = (const float4*)Wrow;
            const float4* x4 = (const float4*)xsrc;
            float acc = 0.f;
            for (int c = 0; c < len4; ++c) {
                float4 w = W4[c], x = x4[c];
                acc += w.x * x.x + w.y * x.y + w.z * x.z + w.w * x.w;
            }
            dst[row * 128 + o] = (m == 6) ? acc * (1.f / 32.f) : acc;
        }
    }

    // streaming reduction, no barriers/LDS: wave w of blk owns slabs r, r+8192
    const int w = t >> 6, lane = t & 63;
    const int gw = blk * 4 + w;
    const float4* noise4 = (const float4*)noise;
    float4* nsum4 = (float4*)(ws + WS_NSUM);

    #pragma unroll
    for (int s = 0; s < 2; ++s) {
        const int r = gw + s * 8192;   // r = bk*32 + j
        const float4* p = noise4 + (size_t)r * 1024 + lane;
        // lane covers d-quad (lane&31), i = (lane>>5) + 2k
        float4 a0 = p[0], a1 = p[64], a2 = p[128], a3 = p[192];
        #pragma unroll
        for (int k = 4; k < 16; k += 4) {
            float4 v0 = p[(k + 0) * 64], v1 = p[(k + 1) * 64];
            float4 v2 = p[(k + 2) * 64], v3 = p[(k + 3) * 64];
            a0.x += v0.x; a0.y += v0.y; a0.z += v0.z; a0.w += v0.w;
            a1.x += v1.x; a1.y += v1.y; a1.z += v1.z; a1.w += v1.w;
            a2.x += v2.x; a2.y += v2.y; a2.z += v2.z; a2.w += v2.w;
            a3.x += v3.x; a3.y += v3.y; a3.z += v3.z; a3.w += v3.w;
        }
        float4 sum;
        sum.x = (a0.x + a1.x) + (a2.x + a3.x);
        sum.y = (a0.y + a1.y) + (a2.y + a3.y);
        sum.z = (a0.z + a1.z) + (a2.z + a3.z);
        sum.w = (a0.w + a1.w) + (a2.w + a3.w);
        sum.x += __shfl_xor(sum.x, 32, 64);
        sum.y += __shfl_xor(sum.y, 32, 64);
        sum.z += __shfl_xor(sum.z, 32, 64);
        sum.w += __shfl_xor(sum.w, 32, 64);
        if (lane < 32) nsum4[(size_t)r * 32 + lane] = sum;
    }
}

// ---------------------------------------------------------------------------
// Kernel B: one block per (b,k). Padded wav layout: row stride 144 floats
// (36 float4), q-chunk at float4 offset q*9 -> conflict-free ds_read_b128.
// ---------------------------------------------------------------------------
__global__ __launch_bounds__(256) void kB(
    const float* __restrict__ W1, const float* __restrict__ W2,
    const float* __restrict__ ws, float* __restrict__ out)
{
    const float* Kk  = ws + WS_K;
    const float* Q   = ws + WS_Q;
    const float* Va  = ws + WS_VA;
    const float* Ko  = ws + WS_KO;
    const float* Qo  = ws + WS_QO;
    const float* AVO = ws + WS_AVO;
    const float* Ddiv= ws + WS_DDIV;
    const float* Nsum= ws + WS_NSUM;

    const int bk = blockIdx.x;
    const int b  = bk >> 5;
    const int t  = threadIdx.x;
    const int h  = t >> 2, q = t & 3;
    const int lane = t & 63, w = t >> 6;

    __shared__ __align__(16) float kr[128], kor[128], wfo[128], sdiv[128];
    __shared__ __align__(16) float dd_s[32 * 128];   // Ddiv rows of batch b
    __shared__ __align__(16) float nw_s[32 * 144];   // padded nsum -> wav
    __shared__ float sA[32], sO[32], woa[32], wo[32], u_s[64], jpart[128];

    // stage Ddiv (coalesced) + nsum (into padded layout)
    {
        const float4* dsrc = (const float4*)(Ddiv + b * 4096);
        const float4* nsrc = (const float4*)(Nsum + (size_t)bk * 4096);
        float4* ddst = (float4*)dd_s;
        float4* ndst = (float4*)nw_s;
        #pragma unroll
        for (int s = 0; s < 4; ++s) {
            const int m = t + 256 * s;           // 0..1023 = j*32 + c
            const int j = m >> 5, c = m & 31;
            ddst[m] = dsrc[m];
            ndst[j * 36 + (c >> 3) * 9 + (c & 7)] = nsrc[m];
        }
    }
    if (t < 128) { kr[t] = Kk[bk * 128 + t]; kor[t] = Ko[bk * 128 + t]; }

    // per-thread W1b chunk: row h, cols 128 + q*32 .. +32
    float w1r[32];
    {
        const float4* p = (const float4*)(W1 + h * 256 + 128 + q * 32);
        #pragma unroll
        for (int c = 0; c < 8; ++c) {
            float4 v = p[c];
            w1r[4*c] = v.x; w1r[4*c+1] = v.y; w1r[4*c+2] = v.z; w1r[4*c+3] = v.w;
        }
    }
    const float w2_h = W2[h];
    __syncthreads();

    // scores: i = t>>3, 8 lanes per dot
    {
        const int i = t >> 3, seg = t & 7;
        const float4* q4  = (const float4*)(Q  + (b * 32 + i) * 128) + seg * 4;
        const float4* qo4 = (const float4*)(Qo + (b * 32 + i) * 128) + seg * 4;
        const float4* k4  = (const float4*)kr  + seg * 4;
        const float4* ko4 = (const float4*)kor + seg * 4;
        float a0 = 0.f, a1 = 0.f;
        #pragma unroll
        for (int c = 0; c < 4; ++c) {
            float4 qv = q4[c], kv = k4[c];
            a0 += qv.x * kv.x + qv.y * kv.y + qv.z * kv.z + qv.w * kv.w;
            float4 pv = qo4[c], mv = ko4[c];
            a1 += pv.x * mv.x + pv.y * mv.y + pv.z * mv.z + pv.w * mv.w;
        }
        #pragma unroll
        for (int off = 1; off < 8; off <<= 1) {
            a0 += __shfl_xor(a0, off, 64);
            a1 += __shfl_xor(a1, off, 64);
        }
        if (seg == 0) {
            const float scale = 0.08838834764831845f;  // 1/sqrt(128)
            sA[i] = a0 * scale;
            sO[i] = a1 * scale;
        }
    }
    __syncthreads();

    // softmaxes in wave 0
    if (t < 64) {
        const int i = t & 31;
        float s = (t < 32) ? sA[i] : sO[i];
        float m = s;
        #pragma unroll
        for (int off = 1; off < 32; off <<= 1) m = fmaxf(m, __shfl_xor(m, off, 64));
        float e = __expf(s - m);
        float sum = e;
        #pragma unroll
        for (int off = 1; off < 32; off <<= 1) sum += __shfl_xor(sum, off, 64);
        float wv = e / sum;
        if (t < 32) { woa[i] = wv; out[16384 + bk * 32 + i] = wv; }
        else        { wo[i]  = wv; out[32768 + bk * 32 + i] = wv; }
    }
    __syncthreads();

    // S/32 (t<128) and wfo (t>=128)
    {
        const int d = t & 127;
        const float* M  = (t < 128) ? Va  : AVO;
        const float* wp = (t < 128) ? woa : wo;
        float acc = 0.f;
        #pragma unroll 8
        for (int i = 0; i < 32; ++i) acc += wp[i] * M[(b * 32 + i) * 128 + d];
        if (t < 128) sdiv[d] = acc * (1.f / 32.f);
        else         wfo[d]  = acc * (1.f / 32.f);
    }
    __syncthreads();

    // u[h] = W1[h,0:128] . wfo
    {
        const float4* w4 = (const float4*)(W1 + h * 256) + q * 8;
        const float4* f4 = (const float4*)wfo + q * 8;
        float acc = 0.f;
        #pragma unroll
        for (int c = 0; c < 8; ++c) {
            float4 wv = w4[c], fv = f4[c];
            acc += wv.x * fv.x + wv.y * fv.y + wv.z * fv.z + wv.w * fv.w;
        }
        acc += __shfl_xor(acc, 1, 64);
        acc += __shfl_xor(acc, 2, 64);
        if (q == 0) u_s[h] = acc;
    }
    // wav in place: nw[j][d] = nsum*(0.1/32) + sdiv[d] + dd[j][d]*woa[j] - 0.05
    {
        const int d = t & 127, jb = t >> 7;
        const int dofs = (d >> 5) * 36 + (d & 31);
        #pragma unroll
        for (int s = 0; s < 16; ++s) {
            const int j = jb + 2 * s;
            const int idx = j * 144 + dofs;
            nw_s[idx] = nw_s[idx] * (0.1f / 32.f)
                      + sdiv[d] + dd_s[j * 128 + d] * woa[j] - 0.05f;
        }
    }
    __syncthreads();

    // value loop: no barriers inside; q-chunk at float4 offset q*9 (padded)
    #pragma unroll 2
    for (int j = 0; j < 32; ++j) {
        const float4* wv4 = (const float4*)(nw_s + j * 144) + q * 9;
        float acc = 0.f;
        #pragma unroll
        for (int c = 0; c < 8; ++c) {
            float4 v = wv4[c];
            acc += w1r[4*c] * v.x + w1r[4*c+1] * v.y
                 + w1r[4*c+2] * v.z + w1r[4*c+3] * v.w;
        }
        acc += __shfl_xor(acc, 1, 64);
        acc += __shfl_xor(acc, 2, 64);
        float hv = u_s[h] + acc;
        hv = (hv > 0.f) ? hv : 0.01f * hv;
        float vp = (q == 0) ? hv * w2_h : 0.f;
        #pragma unroll
        for (int off = 4; off < 64; off <<= 1) vp += __shfl_xor(vp, off, 64);
        if (lane == 0) jpart[j * 4 + w] = vp;
    }
    __syncthreads();
    if (t < 32)
        out[bk * 32 + t] = jpart[t*4] + jpart[t*4+1] + jpart[t*4+2] + jpart[t*4+3];
}

extern "C" void kernel_launch(void* const* d_in, const int* in_sizes, int n_in,
                              void* d_out, int out_size, void* d_ws, size_t ws_size,
                              hipStream_t stream) {
    const float* states   = (const float*)d_in[0];
    const float* policies = (const float*)d_in[1];
    const float* actions  = (const float*)d_in[2];
    const float* noise    = (const float*)d_in[3];
    const float* Wk_oa    = (const float*)d_in[4];
    const float* Wq_oa    = (const float*)d_in[5];
    const float* Wv_oa    = (const float*)d_in[6];
    const float* Wk_o     = (const float*)d_in[7];
    const float* Wq_o     = (const float*)d_in[8];
    const float* Wv_o     = (const float*)d_in[9];
    const float* W1       = (const float*)d_in[10];
    const float* W2       = (const float*)d_in[11];
    float* out = (float*)d_out;
    float* ws  = (float*)d_ws;

    kA<<<2048, 256, 0, stream>>>(states, policies, actions,
                                 Wk_oa, Wq_oa, Wv_oa, Wk_o, Wq_o, Wv_o,
                                 noise, ws);
    kB<<<512, 256, 0, stream>>>(W1, W2, ws, out);
}